// Round 19
// baseline (585.108 us; speedup 1.0000x reference)
//
#include <hip/hip_runtime.h>
#include <hip/hip_bf16.h>

#define BB 8
#define NN 1024
#define KK 20
#define EPSB 1e-5f

typedef __hip_bfloat16 bf16;
typedef __attribute__((ext_vector_type(8))) short sbf8;   // 8 bf16 = 4 VGPRs
typedef __attribute__((ext_vector_type(8))) unsigned short u16x8;
typedef __attribute__((ext_vector_type(4))) unsigned u32x4;
typedef __attribute__((ext_vector_type(4))) float f32x4;
typedef __attribute__((address_space(3))) unsigned lds_u32;
typedef const __attribute__((address_space(1))) unsigned glb_u32;

__device__ __forceinline__ float lrelu(float t){ return t >= 0.f ? t : 0.2f*t; }
__device__ __forceinline__ float ldin(const void* p, int i, int bf){
  return bf ? __bfloat162float(((const bf16*)p)[i]) : ((const float*)p)[i];
}
__device__ __forceinline__ unsigned short f2bf(float f){   // RNE fp32->bf16 bits
  unsigned u = __float_as_uint(f);
  return (unsigned short)((u + 0x7FFFu + ((u>>16)&1u)) >> 16);
}
__device__ __forceinline__ float bf2f(unsigned short us){
  return __uint_as_float((unsigned)us << 16);
}
__device__ __forceinline__ unsigned f2u_ord(float f){
  unsigned u = __float_as_uint(f);
  return (u & 0x80000000u) ? ~u : (u | 0x80000000u);
}
__device__ __forceinline__ float u2f_ord(unsigned u){
  return (u & 0x80000000u) ? __uint_as_float(u & 0x7fffffffu) : __uint_as_float(~u);
}
__device__ __forceinline__ unsigned umaxu(unsigned a, unsigned b){ return a > b ? a : b; }
__device__ __forceinline__ unsigned uminu(unsigned a, unsigned b){ return a < b ? a : b; }

// DPP-based wave64 reduce steps (VALU pipe, no LDS latency chain). HW-verified R4.
template<int CTRL>
__device__ __forceinline__ unsigned dppmax(unsigned x){
  unsigned y = (unsigned)__builtin_amdgcn_update_dpp((int)x, (int)x, CTRL, 0xF, 0xF, false);
  return x > y ? x : y;
}
template<int CTRL>
__device__ __forceinline__ unsigned dppmin(unsigned x){
  unsigned y = (unsigned)__builtin_amdgcn_update_dpp((int)x, (int)x, CTRL, 0xF, 0xF, false);
  return x < y ? x : y;
}

// inline dtype detect: full-wave ballot over x's first 64 words.
__device__ __forceinline__ int detect_bf(const void* x){
  unsigned w = ((const unsigned*)x)[threadIdx.x & 63];
  unsigned e = (w >> 23) & 0xFFu;
  unsigned long long m = __ballot(e >= 0xD0u);
  return (__popcll(m) >= 32) ? 1 : 0;
}

// ---------------- conv0 stats
__global__ __launch_bounds__(256) void conv0_stats_kernel(
    const void* __restrict__ x,
    const void* __restrict__ w00, const void* __restrict__ w01,
    float* __restrict__ cstat){
  const int bf = detect_bf(x);
  int i = blockIdx.x*256 + threadIdx.x;
  int b = i >> 10, n = i & 1023;
  float wz[4], wy[4];
#pragma unroll
  for (int j=0;j<4;j++){ wz[j]=ldin(w00,j,bf); wy[j]=ldin(w01,j,bf); }
  float x0 = ldin(x,(b*3+0)*NN + n,bf);
  float x1 = ldin(x,(b*3+1)*NN + n,bf);
  float x2 = ldin(x,(b*3+2)*NN + n,bf);
  float vals[6];
  vals[0] = wz[0]*x0 + wz[1]*x1;  vals[1] = wz[2]*x0 + wz[3]*x1;
  vals[2] = wy[0]*x0 + wy[1]*x2;  vals[3] = wy[2]*x0 + wy[3]*x2;
  vals[4] = wy[0]*x1 + wy[1]*x2;  vals[5] = wy[2]*x1 + wy[3]*x2;
  int lane = threadIdx.x & 63;
#pragma unroll
  for (int j=0;j<6;j++){
    float s1 = vals[j], s2 = vals[j]*vals[j];
#pragma unroll
    for (int off=32; off; off>>=1){
      s1 += __shfl_xor(s1, off, 64);
      s2 += __shfl_xor(s2, off, 64);
    }
    if (lane == 0){
      atomicAdd(&cstat[2*j], s1);
      atomicAdd(&cstat[2*j+1], s2);
    }
  }
}

// ---------------- conv0 apply: BN+lrelu+gate, writes xc0 rows + row norm (R12)
__global__ __launch_bounds__(256) void conv0_apply_kernel(
    const void* __restrict__ x,
    const void* __restrict__ w00, const void* __restrict__ g00, const void* __restrict__ b00,
    const void* __restrict__ w01, const void* __restrict__ g01, const void* __restrict__ b01,
    const float* __restrict__ cstat, float* __restrict__ xc0,
    float* __restrict__ xnorm){
  const int bf = detect_bf(x);
  int i = blockIdx.x*256 + threadIdx.x;
  int b = i >> 10, n = i & 1023;
  float wz[4], wy[4];
#pragma unroll
  for (int j=0;j<4;j++){ wz[j]=ldin(w00,j,bf); wy[j]=ldin(w01,j,bf); }
  float sA[6], sC[6];
#pragma unroll
  for (int j=0;j<6;j++){
    float m = cstat[2*j] * (1.f/(BB*NN));
    float v = cstat[2*j+1] * (1.f/(BB*NN)) - m*m;
    float g, bv;
    if (j<2){ g=ldin(g00,j,bf); bv=ldin(b00,j,bf); }
    else if (j<4){ g=ldin(g01,j-2,bf); bv=ldin(b01,j-2,bf); }
    else { g=ldin(g01,j-4,bf); bv=ldin(b01,j-4,bf); }
    float a = g * rsqrtf(fmaxf(v,0.f) + EPSB);
    sA[j]=a; sC[j]=bv - m*a;
  }
  float x0 = ldin(x,(b*3+0)*NN + n,bf);
  float x1 = ldin(x,(b*3+1)*NN + n,bf);
  float x2 = ldin(x,(b*3+2)*NN + n,bf);
  float z0 = wz[0]*x0 + wz[1]*x1, z1 = wz[2]*x0 + wz[3]*x1;
  float y0 = wy[0]*x0 + wy[1]*x2, y1 = wy[2]*x0 + wy[3]*x2;
  float u0 = wy[0]*x1 + wy[1]*x2, u1 = wy[2]*x1 + wy[3]*x2;
  float* row = xc0 + (size_t)i*16;
  float4 r0, r1, r2, r3;
  r0.x=x0; r0.y=x1; r0.z=x2;
  r0.w=lrelu(sA[4]*u0+sC[4])*x0;
  r1.x=lrelu(sA[5]*u1+sC[5])*x0;
  r1.y=lrelu(sA[2]*y0+sC[2])*x1;
  r1.z=lrelu(sA[3]*y1+sC[3])*x1;
  r1.w=lrelu(sA[0]*z0+sC[0])*x2;
  r2.x=lrelu(sA[1]*z1+sC[1])*x2;
  r2.y=0.f; r2.z=0.f; r2.w=0.f;
  r3.x=0.f; r3.y=0.f; r3.z=0.f; r3.w=0.f;
  *(float4*)&row[0]  = r0;
  *(float4*)&row[4]  = r1;
  *(float4*)&row[8]  = r2;
  *(float4*)&row[12] = r3;
  float nr = x0*x0 + x1*x1 + x2*x2
           + r0.w*r0.w + r1.x*r1.x + r1.y*r1.y + r1.z*r1.z + r1.w*r1.w
           + r2.x*r2.x;
  xnorm[i] = nr;
}

// ---------------- weight prep element
__device__ __forceinline__ void wuv_elem(const void* W, float* WdT, float* WcdT,
                                         int CIN, int COUT, int t, int bf){
  int c = t / COUT, o = t % COUT;
  if (c < CIN){
    float wd = ldin(W, o*(2*CIN)+c, bf);
    float wc = ldin(W, o*(2*CIN)+CIN+c, bf);
    WdT[t] = wd; WcdT[t] = wc - wd;
  } else {
    WdT[t] = 0.f; WcdT[t] = 0.f;
  }
}

// ---------------- fused prep
#define NZERO (1024+1024+2048+4096+2048+8192+8192+16+8192)
__global__ __launch_bounds__(256) void prep_kernel(
    const void* __restrict__ x,
    const void* __restrict__ w1, const void* __restrict__ w2,
    const void* __restrict__ w3, const void* __restrict__ w4,
    const void* __restrict__ w5,
    unsigned* __restrict__ zbase,
    float* __restrict__ w1d, float* __restrict__ w1c,
    float* __restrict__ w2d, float* __restrict__ w2c,
    float* __restrict__ w3d, float* __restrict__ w3c,
    float* __restrict__ w4d, float* __restrict__ w4c,
    unsigned short* __restrict__ wb5){
  const int bf = detect_bf(x);
  int t = blockIdx.x*256 + threadIdx.x;
  if (t < NZERO){ zbase[t] = 0u; return; }
  t -= NZERO;
  if (t < 768){ wuv_elem(w1, w1d, w1c, 9, 64, t, bf); return; }
  t -= 768;
  if (t < 4096){ wuv_elem(w2, w2d, w2c, 64, 64, t, bf); return; }
  t -= 4096;
  if (t < 8192){ wuv_elem(w3, w3d, w3c, 64, 128, t, bf); return; }
  t -= 8192;
  if (t < 32768){ wuv_elem(w4, w4d, w4c, 128, 256, t, bf); return; }
  t -= 32768;
  if (t < 1024*512) wb5[t] = f2bf(ldin(w5, t, bf));
}

// ---------------- fused negdist: 128x128 tiles, EXTERNAL row norms (R12-verified).
// 512 threads (R16: occupancy verified), R17 split store swizzle (R18-verified:
// knndist left top-5). Bitwise-identical negD.
template<int KCH, int NCH>
__global__ __launch_bounds__(512, 2) void knndist_kernel(
    const float* __restrict__ src, int ld, int coff,
    const float* __restrict__ xnorm, float* __restrict__ negD){
  constexpr int NG = KCH >> 2;
  constexpr int GM = NG - 1;
  extern __shared__ float lds[];
  float* At = lds;
  float* Bt = lds + 128*KCH;
  float* xn = Bt + 128*KCH;
  int b = blockIdx.z, i0 = blockIdx.y*128, j0 = blockIdx.x*128;
  int tid = threadIdx.x;
  int ti = tid >> 4, tj = tid & 15;
  int gsa = ti & GM;                       // At store is (r>>2)&GM
  int gsb = tj & GM;                       // Bt store is (r>>3)&GM
  if (tid < 256)
    xn[tid] = xnorm[(size_t)b*NN + (tid < 128 ? i0 + tid : j0 + tid - 128)];
  float acc[4][8];
#pragma unroll
  for (int u=0;u<4;u++)
#pragma unroll
    for (int v=0;v<8;v++) acc[u][v]=0.f;
#pragma unroll 1
  for (int ch=0; ch<NCH; ch++){
    int c0 = ch*KCH;
    __syncthreads();
#pragma unroll
    for (int it=0; it<(2*128*NG)/512; it++){
      int t = it*512 + tid;
      int half = (t >= 128*NG);
      int tt = half ? t - 128*NG : t;
      int r = tt / NG, g = tt % NG;
      int base = half ? j0 : i0;
      float4 f = *(const float4*)&src[(size_t)(b*NN + base + r)*ld + coff + c0 + g*4];
      int gs = g ^ (half ? ((r>>3) & GM) : ((r>>2) & GM));
      float* dst = (half ? Bt : At) + r*KCH + gs*4;
      *(float4*)dst = f;
    }
    __syncthreads();
#pragma unroll 2
    for (int g=0; g<NG; g++){
      float4 av[4];
#pragma unroll
      for (int u=0;u<4;u++)
        av[u] = *(const float4*)&At[(ti*4+u)*KCH + ((g ^ gsa)<<2)];
#pragma unroll
      for (int v=0;v<8;v++){
        float4 bv = *(const float4*)&Bt[(tj*8+v)*KCH + ((g ^ gsb)<<2)];
#pragma unroll
        for (int u=0;u<4;u++)
          acc[u][v] += av[u].x*bv.x + av[u].y*bv.y + av[u].z*bv.z + av[u].w*bv.w;
      }
    }
  }
  float xi[4], xj[8];
#pragma unroll
  for (int u=0;u<4;u++) xi[u] = xn[ti*4+u];
#pragma unroll
  for (int v=0;v<8;v++) xj[v] = xn[128 + tj*8+v];
#pragma unroll
  for (int u=0;u<4;u++){
    float* orow = &negD[((size_t)(b*NN + i0 + ti*4 + u))*NN + j0 + tj*8];
#pragma unroll
    for (int vg=0; vg<2; vg++){
      float4 ov;
      ov.x = 2.f*acc[u][vg*4+0] - xi[u] - xj[vg*4+0];
      ov.y = 2.f*acc[u][vg*4+1] - xi[u] - xj[vg*4+1];
      ov.z = 2.f*acc[u][vg*4+2] - xi[u] - xj[vg*4+2];
      ov.w = 2.f*acc[u][vg*4+3] - xi[u] - xj[vg*4+3];
      *(float4*)&orow[vg*4] = ov;
    }
  }
}

// ---------------- fused u/v GEMM + top-20.
// R19: topk waves each own TWO rows with manually interleaved DPP chains —
// R18 showed topk is LATENCY-bound (static VALU ~10us vs observed 47us at 75%
// VALUBusy, ~2.5 waves/SIMD): each round is two serial 4-step DPP chains +
// readlane round trips with nothing to hide under. Two independent chains per
// wave hide each other. Per-row semantics identical -> identical idx output.
// topk blocks: 1024 (each block = 4 waves x 2 rows = 8 rows).
#define UVB 1024     // uvgemm blocks = 8192/PT
#define TKB 1024     // topk blocks (8 rows each)
template<int CINP,int COUT>
__global__ __launch_bounds__(256, 4) void topkuv_kernel(
    const float* __restrict__ negD, int* __restrict__ idx,
    const float* __restrict__ srcT, int ld, int coff,
    const float* __restrict__ WdT, const float* __restrict__ WcdT,
    float* __restrict__ ut, float* __restrict__ vt){
  constexpr int PT = 8;
  __shared__ float xs[PT*CINP];
  int tid = threadIdx.x;
  if (blockIdx.x < UVB){
    constexpr int G = 256/COUT, NP = PT/G;
    int base = blockIdx.x*PT;
    for (int t=tid; t<PT*CINP; t+=256){
      int p = t / CINP, c = t % CINP;
      xs[t] = srcT[(size_t)(base+p)*ld + coff + c];
    }
    __syncthreads();
    int o = tid % COUT, grp = tid / COUT;
    float u[NP], v[NP];
#pragma unroll
    for (int pp=0;pp<NP;pp++){ u[pp]=0.f; v[pp]=0.f; }
    for (int c=0;c<CINP;c+=4){
      float wd0 = WdT[(c+0)*COUT+o], wc0 = WcdT[(c+0)*COUT+o];
      float wd1 = WdT[(c+1)*COUT+o], wc1 = WcdT[(c+1)*COUT+o];
      float wd2 = WdT[(c+2)*COUT+o], wc2 = WcdT[(c+2)*COUT+o];
      float wd3 = WdT[(c+3)*COUT+o], wc3 = WcdT[(c+3)*COUT+o];
#pragma unroll
      for (int pp=0;pp<NP;pp++){
        float4 xv = *(const float4*)&xs[(grp+pp*G)*CINP + c];
        u[pp] = fmaf(xv.x,wd0,fmaf(xv.y,wd1,fmaf(xv.z,wd2,fmaf(xv.w,wd3,u[pp]))));
        v[pp] = fmaf(xv.x,wc0,fmaf(xv.y,wc1,fmaf(xv.z,wc2,fmaf(xv.w,wc3,v[pp]))));
      }
    }
#pragma unroll
    for (int pp=0;pp<NP;pp++){
      int p = grp + pp*G;
      ut[(size_t)(base+p)*COUT + o] = u[pp];
      vt[(size_t)(base+p)*COUT + o] = v[pp];
    }
    return;
  }
  // ---------- topk: one wave = TWO rows, interleaved DPP chains
  int wid = (blockIdx.x - UVB)*4 + (tid >> 6);   // 0..4095
  int lane = tid & 63;
  int rowA = wid*2, rowB = wid*2 + 1;
  const float* rpA = negD + (size_t)rowA*NN;
  const float* rpB = negD + (size_t)rowB*NN;
  unsigned kvA[16], kvB[16];
#pragma unroll
  for (int j=0;j<4;j++){
    float4 fA = *(const float4*)&rpA[j*256 + lane*4];
    float4 fB = *(const float4*)&rpB[j*256 + lane*4];
    kvA[j*4+0]=f2u_ord(fA.x); kvA[j*4+1]=f2u_ord(fA.y);
    kvA[j*4+2]=f2u_ord(fA.z); kvA[j*4+3]=f2u_ord(fA.w);
    kvB[j*4+0]=f2u_ord(fB.x); kvB[j*4+1]=f2u_ord(fB.y);
    kvB[j*4+2]=f2u_ord(fB.z); kvB[j*4+3]=f2u_ord(fB.w);
  }
  const unsigned lane4 = (unsigned)(lane << 2);
  unsigned v1A=0u,g1A=0u,v2A=0u,g2A=0u, v1B=0u,g1B=0u,v2B=0u,g2B=0u;
#pragma unroll
  for (int s=0;s<16;s++){
    unsigned go = lane4 + (unsigned)(((s>>2)<<8) + (s&3));
    bool a1 = kvA[s] > v1A, a2 = kvA[s] > v2A;
    v2A = a1 ? v1A : (a2 ? kvA[s] : v2A);
    g2A = a1 ? g1A : (a2 ? go     : g2A);
    v1A = a1 ? kvA[s] : v1A;
    g1A = a1 ? go     : g1A;
    bool b1 = kvB[s] > v1B, b2 = kvB[s] > v2B;
    v2B = b1 ? v1B : (b2 ? kvB[s] : v2B);
    g2B = b1 ? g1B : (b2 ? go     : g2B);
    v1B = b1 ? kvB[s] : v1B;
    g1B = b1 ? go     : g1B;
  }
  unsigned consA = 0u, consB = 0u;
  int myA = 0, myB = 0;
  int* orA = idx + (size_t)rowA*KK;
  int* orB = idx + (size_t)rowB*KK;
#pragma unroll 1
  for (int k=0;k<KK;k++){
    // interleaved wave-max chains
    unsigned mA = v1A, mB = v1B;
    mA = dppmax<0xB1>(mA);  mB = dppmax<0xB1>(mB);
    mA = dppmax<0x4E>(mA);  mB = dppmax<0x4E>(mB);
    mA = dppmax<0x124>(mA); mB = dppmax<0x124>(mB);
    mA = dppmax<0x128>(mA); mB = dppmax<0x128>(mB);
    unsigned wA0 = (unsigned)__builtin_amdgcn_readlane((int)mA, 0);
    unsigned wB0 = (unsigned)__builtin_amdgcn_readlane((int)mB, 0);
    unsigned wA1 = (unsigned)__builtin_amdgcn_readlane((int)mA, 16);
    unsigned wB1 = (unsigned)__builtin_amdgcn_readlane((int)mB, 16);
    unsigned wA2 = (unsigned)__builtin_amdgcn_readlane((int)mA, 32);
    unsigned wB2 = (unsigned)__builtin_amdgcn_readlane((int)mB, 32);
    unsigned wA3 = (unsigned)__builtin_amdgcn_readlane((int)mA, 48);
    unsigned wB3 = (unsigned)__builtin_amdgcn_readlane((int)mB, 48);
    unsigned winA = umaxu(umaxu(wA0,wA1), umaxu(wA2,wA3));
    unsigned winB = umaxu(umaxu(wB0,wB1), umaxu(wB2,wB3));
    // interleaved min-index chains (exact tie-break)
    unsigned cA = (v1A == winA) ? g1A : 0xFFFFFFFFu;
    unsigned cB = (v1B == winB) ? g1B : 0xFFFFFFFFu;
    cA = dppmin<0xB1>(cA);  cB = dppmin<0xB1>(cB);
    cA = dppmin<0x4E>(cA);  cB = dppmin<0x4E>(cB);
    cA = dppmin<0x124>(cA); cB = dppmin<0x124>(cB);
    cA = dppmin<0x128>(cA); cB = dppmin<0x128>(cB);
    unsigned cA0 = (unsigned)__builtin_amdgcn_readlane((int)cA, 0);
    unsigned cB0 = (unsigned)__builtin_amdgcn_readlane((int)cB, 0);
    unsigned cA1 = (unsigned)__builtin_amdgcn_readlane((int)cA, 16);
    unsigned cB1 = (unsigned)__builtin_amdgcn_readlane((int)cB, 16);
    unsigned cA2 = (unsigned)__builtin_amdgcn_readlane((int)cA, 32);
    unsigned cB2 = (unsigned)__builtin_amdgcn_readlane((int)cB, 32);
    unsigned cA3 = (unsigned)__builtin_amdgcn_readlane((int)cA, 48);
    unsigned cB3 = (unsigned)__builtin_amdgcn_readlane((int)cB, 48);
    unsigned wiA = uminu(uminu(cA0,cA1), uminu(cA2,cA3));
    unsigned wiB = uminu(uminu(cB0,cB1), uminu(cB2,cB3));
    myA = (lane == k) ? (int)wiA : myA;
    myB = (lane == k) ? (int)wiB : myB;
    bool mnA = (g1A == wiA);
    bool mnB = (g1B == wiB);
    bool rfA = mnA && (v2A == 0u);
    bool rfB = mnB && (v2B == 0u);
    v1A = mnA ? v2A : v1A;  g1A = mnA ? g2A : g1A;  v2A = mnA ? 0u : v2A;
    v1B = mnB ? v2B : v1B;  g1B = mnB ? g2B : g1B;  v2B = mnB ? 0u : v2B;
    unsigned slA = ((wiA >> 8) << 2) | (wiA & 3u);
    unsigned slB = ((wiB >> 8) << 2) | (wiB & 3u);
    consA |= (mnA ? (1u << slA) : 0u);
    consB |= (mnB ? (1u << slB) : 0u);
    if (__ballot(rfA)){                            // rare refill, row A
      unsigned n1=0u, ng1=0u, n2=0u, ng2=0u;
#pragma unroll
      for (int s=0;s<16;s++){
        unsigned go = lane4 + (unsigned)(((s>>2)<<8) + (s&3));
        unsigned val = (consA & (1u<<s)) ? 0u : kvA[s];
        bool t1 = val > n1, t2 = val > n2;
        n2 = t1 ? n1 : (t2 ? val : n2);
        ng2 = t1 ? ng1 : (t2 ? go  : ng2);
        n1 = t1 ? val : n1;
        ng1 = t1 ? go  : ng1;
      }
      v1A = rfA ? n1 : v1A;  g1A = rfA ? ng1 : g1A;
      v2A = rfA ? n2 : v2A;  g2A = rfA ? ng2 : g2A;
    }
    if (__ballot(rfB)){                            // rare refill, row B
      unsigned n1=0u, ng1=0u, n2=0u, ng2=0u;
#pragma unroll
      for (int s=0;s<16;s++){
        unsigned go = lane4 + (unsigned)(((s>>2)<<8) + (s&3));
        unsigned val = (consB & (1u<<s)) ? 0u : kvB[s];
        bool t1 = val > n1, t2 = val > n2;
        n2 = t1 ? n1 : (t2 ? val : n2);
        ng2 = t1 ? ng1 : (t2 ? go  : ng2);
        n1 = t1 ? val : n1;
        ng1 = t1 ? go  : ng1;
      }
      v1B = rfB ? n1 : v1B;  g1B = rfB ? ng1 : g1B;
      v2B = rfB ? n2 : v2B;  g2B = rfB ? ng2 : g2B;
    }
  }
  if (lane < KK){ orA[lane] = myA; orB[lane] = myB; }
}

// ---------------- gather (R8 DMA + R10 per-batch stats; both verified)
template<int COUT>
__global__ __launch_bounds__(256, 4) void ebgather_kernel(
    const int* __restrict__ idx, const float* __restrict__ ut, const float* __restrict__ vt,
    float* __restrict__ hmaxb, float* __restrict__ hminb, float* __restrict__ stats){
  constexpr int CHG = COUT/64;
  __shared__ float sred[128];
  __shared__ float hstage[4*KK*64];
  int w = threadIdx.x >> 6, lane = threadIdx.x & 63;
  int pb  = blockIdx.x / CHG;
  int chg = blockIdx.x % CHG;
  int nu = __builtin_amdgcn_readfirstlane(pb*4 + w);
  int b = nu >> 10;
  int bblk = (pb*4) >> 10;
  if (threadIdx.x < 128) sred[threadIdx.x] = 0.f;
  __syncthreads();
  const int* irow = idx + (size_t)nu*KK;
  int m[KK];
#pragma unroll
  for (int k=0;k<KK;k++) m[k] = __builtin_amdgcn_readfirstlane(irow[k]);
  int co = chg*64 + lane;
  float vr = vt[(size_t)nu*COUT + co];
  float* hbase = &hstage[w*KK*64];
#pragma unroll
  for (int k=0;k<KK;k++){
    const float* src = &ut[(size_t)(b*NN + m[k])*COUT + co];
    __builtin_amdgcn_global_load_lds((glb_u32*)src, (lds_u32*)&hbase[k*64], 4, 0, 0);
  }
  asm volatile("s_waitcnt vmcnt(0)" ::: "memory");
  float hx=-1e30f, hn=1e30f, s1=0.f, s2=0.f;
#pragma unroll
  for (int k=0;k<KK;k++){
    float t = hbase[k*64 + lane] + vr;
    hx = fmaxf(hx, t);
    hn = fminf(hn, t);
    s1 += t;
    s2 = fmaf(t, t, s2);
  }
  hmaxb[(size_t)nu*COUT + co] = hx;
  hminb[(size_t)nu*COUT + co] = hn;
  atomicAdd(&sred[lane], s1);
  atomicAdd(&sred[64+lane], s2);
  __syncthreads();
  if (threadIdx.x < 128){
    int which = threadIdx.x >> 6, l = threadIdx.x & 63;
    atomicAdd(&stats[(size_t)bblk*2*COUT + which*COUT + chg*64 + l],
              sred[which*64 + l]);
  }
}

// ---------------- apply (per-batch stat partials; emits norms for next knndist)
template<int COUT, int NORMMODE>
__global__ __launch_bounds__(256) void ebapply_kernel(
    const void* __restrict__ x,
    const float* __restrict__ hmaxb, const float* __restrict__ hminb,
    const float* __restrict__ stats, const void* __restrict__ g, const void* __restrict__ bb,
    float* __restrict__ outp, int outoff, float* __restrict__ xnorm){
  const int bf = detect_bf(x);
  int t = blockIdx.x*256 + threadIdx.x;
  int n = t / COUT, o = t % COUT;
  const float inv_count = 1.f/(BB*NN*KK);
  float s1 = 0.f, s2 = 0.f;
#pragma unroll
  for (int p=0;p<BB;p++){
    s1 += stats[(size_t)p*2*COUT + o];
    s2 += stats[(size_t)p*2*COUT + COUT + o];
  }
  float m = s1*inv_count;
  float var = s2*inv_count - m*m;
  float a = ldin(g,o,bf)*rsqrtf(fmaxf(var,0.f) + EPSB);
  float c = ldin(bb,o,bf) - m*a;
  float h = (a >= 0.f) ? hmaxb[t] : hminb[t];
  float r = lrelu(fmaf(a,h,c));
  outp[(size_t)n*512 + outoff + o] = r;
  if (NORMMODE){
    float s = r*r;
#pragma unroll
    for (int off=32; off; off>>=1) s += __shfl_xor(s, off, 64);
    int lane = threadIdx.x & 63;
    if (NORMMODE == 1){ if (lane == 0) xnorm[n] = s; }
    else              { if (lane == 0) atomicAdd(&xnorm[n], s); }
  }
}

// ---------------- conv5 via MFMA bf16 — 128x128x64 tiled GEMM (R1-verified).
__global__ __launch_bounds__(256) void fc5_mfma(
    const float* __restrict__ xcat, const unsigned short* __restrict__ wb5,
    float* __restrict__ st5, unsigned short* __restrict__ hbufb){
  __shared__ unsigned As[128*32];
  __shared__ unsigned Bs[128*32];
  int tid = threadIdx.x;
  int n0 = blockIdx.x * 128;
  int m0 = blockIdx.y * 128;
  int lane = tid & 63, w = tid >> 6;
  int wr = w >> 1, wc = w & 1;
  int col = lane & 15, quad = lane >> 4;

  int r0 = tid >> 3, g0 = tid & 7;
  int gsw = g0 ^ (r0 & 7);

  float4  arA[4][2];
  u16x8   brB[4];

  auto load_regs = [&](int k0){
#pragma unroll
    for (int j=0;j<4;j++){
      const float* ap = xcat + (size_t)(m0 + j*32 + r0)*512 + k0 + gsw*8;
      arA[j][0] = *(const float4*)ap;
      arA[j][1] = *(const float4*)(ap + 4);
      brB[j] = *(const u16x8*)(wb5 + (size_t)(n0 + j*32 + r0)*512 + k0 + gsw*8);
    }
  };

  f32x4 acc[4][4];
#pragma unroll
  for (int mi=0;mi<4;mi++)
#pragma unroll
    for (int ni=0;ni<4;ni++) acc[mi][ni] = (f32x4){0.f,0.f,0.f,0.f};

  load_regs(0);
  for (int ks=0; ks<8; ks++){
    __syncthreads();
#pragma unroll
    for (int j=0;j<4;j++){
      u32x4 pk;
      pk.x = (unsigned)f2bf(arA[j][0].x) | ((unsigned)f2bf(arA[j][0].y) << 16);
      pk.y = (unsigned)f2bf(arA[j][0].z) | ((unsigned)f2bf(arA[j][0].w) << 16);
      pk.z = (unsigned)f2bf(arA[j][1].x) | ((unsigned)f2bf(arA[j][1].y) << 16);
      pk.w = (unsigned)f2bf(arA[j][1].z) | ((unsigned)f2bf(arA[j][1].w) << 16);
      *(u32x4*)&As[(j*256 + tid)*4] = pk;
      *(u16x8*)&Bs[(j*256 + tid)*4] = brB[j];
    }
    if (ks < 7) load_regs((ks+1)*64);
    __syncthreads();
#pragma unroll
    for (int kf=0; kf<2; kf++){
      int G = kf*4 + quad;
      sbf8 af[4], bfr[4];
#pragma unroll
      for (int mi=0;mi<4;mi++){
        int rr = wr*64 + mi*16 + col;
        af[mi] = *(const sbf8*)&As[rr*32 + ((G ^ (rr&7))<<2)];
      }
#pragma unroll
      for (int ni=0;ni<4;ni++){
        int rr = wc*64 + ni*16 + col;
        bfr[ni] = *(const sbf8*)&Bs[rr*32 + ((G ^ (rr&7))<<2)];
      }
#pragma unroll
      for (int mi=0;mi<4;mi++)
#pragma unroll
        for (int ni=0;ni<4;ni++)
          acc[mi][ni] = __builtin_amdgcn_mfma_f32_16x16x32_bf16(
              af[mi], bfr[ni], acc[mi][ni], 0, 0, 0);
    }
  }

#pragma unroll
  for (int ni=0;ni<4;ni++){
    float s1 = 0.f, s2 = 0.f;
#pragma unroll
    for (int mi=0;mi<4;mi++){
      f32x4 a = acc[mi][ni];
      s1 += a.x + a.y + a.z + a.w;
      s2 += a.x*a.x + a.y*a.y + a.z*a.z + a.w*a.w;
    }
    s1 += __shfl_xor(s1,16,64); s2 += __shfl_xor(s2,16,64);
    s1 += __shfl_xor(s1,32,64); s2 += __shfl_xor(s2,32,64);
    if (lane < 16){
      int o = n0 + wc*64 + ni*16 + lane;
      atomicAdd(&st5[o], s1);
      atomicAdd(&st5[1024+o], s2);
    }
  }
#pragma unroll
  for (int mi=0;mi<4;mi++){
    int row = m0 + wr*64 + mi*16 + quad*4;
#pragma unroll
    for (int ni=0;ni<4;ni++){
      int o = n0 + wc*64 + ni*16 + col;
      f32x4 a = acc[mi][ni];
      unsigned short* hp = hbufb + (size_t)row*1024 + o;
      hp[0]      = f2bf(a.x);
      hp[1024]   = f2bf(a.y);
      hp[2*1024] = f2bf(a.z);
      hp[3*1024] = f2bf(a.w);
    }
  }
}

// ---------------- pool over n
__global__ __launch_bounds__(256) void pool5_kernel(
    const void* __restrict__ x,
    const unsigned short* __restrict__ hbufb, const float* __restrict__ st5,
    const void* __restrict__ g5, const void* __restrict__ b5,
    unsigned* __restrict__ pmax, float* __restrict__ psum){
  const int bf = detect_bf(x);
  int b = blockIdx.x >> 5;
  int ns = blockIdx.x & 31;
  int o4 = threadIdx.x*4;
  const float inv_count = 1.f/(BB*NN);
  float a[4], c[4];
#pragma unroll
  for (int j=0;j<4;j++){
    int o = o4+j;
    float m = st5[o]*inv_count;
    float var = st5[1024+o]*inv_count - m*m;
    a[j] = ldin(g5,o,bf)*rsqrtf(fmaxf(var,0.f)+EPSB);
    c[j] = ldin(b5,o,bf) - m*a[j];
  }
  float mx0=-1e30f,mx1=-1e30f,mx2=-1e30f,mx3=-1e30f;
  float sm0=0.f,sm1=0.f,sm2=0.f,sm3=0.f;
  for (int n = ns*32; n < ns*32+32; n++){
    ushort4 hu = *(const ushort4*)&hbufb[(size_t)(b*NN + n)*1024 + o4];
    float t0 = lrelu(fmaf(a[0],bf2f(hu.x),c[0]));
    float t1 = lrelu(fmaf(a[1],bf2f(hu.y),c[1]));
    float t2 = lrelu(fmaf(a[2],bf2f(hu.z),c[2]));
    float t3 = lrelu(fmaf(a[3],bf2f(hu.w),c[3]));
    mx0=fmaxf(mx0,t0); mx1=fmaxf(mx1,t1); mx2=fmaxf(mx2,t2); mx3=fmaxf(mx3,t3);
    sm0+=t0; sm1+=t1; sm2+=t2; sm3+=t3;
  }
  atomicMax(&pmax[b*1024+o4+0], f2u_ord(mx0));
  atomicMax(&pmax[b*1024+o4+1], f2u_ord(mx1));
  atomicMax(&pmax[b*1024+o4+2], f2u_ord(mx2));
  atomicMax(&pmax[b*1024+o4+3], f2u_ord(mx3));
  atomicAdd(&psum[b*1024+o4+0], sm0);
  atomicAdd(&psum[b*1024+o4+1], sm1);
  atomicAdd(&psum[b*1024+o4+2], sm2);
  atomicAdd(&psum[b*1024+o4+3], sm3);
}

// ---------------- FC head
__global__ __launch_bounds__(256) void fc6_kernel(
    const void* __restrict__ x,
    const unsigned* __restrict__ pmax, const float* __restrict__ psum,
    const void* __restrict__ W,
    const void* __restrict__ g, const void* __restrict__ bb, float* __restrict__ y6){
  __shared__ float red[8][256];
  int o = blockIdx.x, tid = threadIdx.x;
  const int bf = detect_bf(x);
  float part[8];
#pragma unroll
  for (int b=0;b<8;b++) part[b]=0.f;
  for (int c=tid;c<2048;c+=256){
    float wv = ldin(W,o*2048+c,bf);
#pragma unroll
    for (int b=0;b<8;b++){
      float pv = (c < 1024) ? u2f_ord(pmax[b*1024+c])
                            : psum[b*1024 + (c-1024)] * (1.f/1024.f);
      part[b] = fmaf(pv, wv, part[b]);
    }
  }
#pragma unroll
  for (int b=0;b<8;b++) red[b][tid]=part[b];
  __syncthreads();
  for (int s=128;s;s>>=1){
    if (tid<s){
#pragma unroll
      for (int b=0;b<8;b++) red[b][tid]+=red[b][tid+s];
    }
    __syncthreads();
  }
  if (tid==0){
    float y[8], m=0.f;
#pragma unroll
    for (int b=0;b<8;b++){ y[b]=red[b][0]; m+=y[b]; }
    m *= 0.125f;
    float v=0.f;
#pragma unroll
    for (int b=0;b<8;b++){ float d=y[b]-m; v += d*d; }
    v *= 0.125f;
    float a=ldin(g,o,bf)*rsqrtf(fmaxf(v,0.f)+EPSB), c0=ldin(bb,o,bf)-m*a;
#pragma unroll
    for (int b=0;b<8;b++) y6[b*512+o]=lrelu(fmaf(a,y[b],c0));
  }
}

__global__ __launch_bounds__(256) void fc7_kernel(
    const void* __restrict__ x,
    const float* __restrict__ y6, const void* __restrict__ W, const void* __restrict__ bias,
    const void* __restrict__ g, const void* __restrict__ bb, float* __restrict__ y7){
  __shared__ float red[8][256];
  int o = blockIdx.x, tid = threadIdx.x;
  const int bf = detect_bf(x);
  float part[8];
#pragma unroll
  for (int b=0;b<8;b++) part[b]=0.f;
  for (int c=tid;c<512;c+=256){
    float wv = ldin(W,o*512+c,bf);
#pragma unroll
    for (int b=0;b<8;b++) part[b] = fmaf(y6[b*512+c], wv, part[b]);
  }
#pragma unroll
  for (int b=0;b<8;b++) red[b][tid]=part[b];
  __syncthreads();
  for (int s=128;s;s>>=1){
    if (tid<s){
#pragma unroll
      for (int b=0;b<8;b++) red[b][tid]+=red[b][tid+s];
    }
    __syncthreads();
  }
  if (tid==0){
    float bs = ldin(bias,o,bf);
    float y[8], m=0.f;
#pragma unroll
    for (int b=0;b<8;b++){ y[b]=red[b][0]+bs; m+=y[b]; }
    m *= 0.125f;
    float v=0.f;
#pragma unroll
    for (int b=0;b<8;b++){ float d=y[b]-m; v += d*d; }
    v *= 0.125f;
    float a=ldin(g,o,bf)*rsqrtf(fmaxf(v,0.f)+EPSB), c0=ldin(bb,o,bf)-m*a;
#pragma unroll
    for (int b=0;b<8;b++) y7[b*256+o]=lrelu(fmaf(a,y[b],c0));
  }
}

__global__ __launch_bounds__(256) void fc8_kernel(
    const void* __restrict__ x,
    const float* __restrict__ y7, const void* __restrict__ W, const void* __restrict__ bias,
    void* __restrict__ out){
  __shared__ float red[8][256];
  int o = blockIdx.x, tid = threadIdx.x;
  const int bf = detect_bf(x);
  float wv = ldin(W,o*256+tid,bf);
#pragma unroll
  for (int b=0;b<8;b++) red[b][tid] = y7[b*256+tid]*wv;
  __syncthreads();
  for (int s=128;s;s>>=1){
    if (tid<s){
#pragma unroll
      for (int b=0;b<8;b++) red[b][tid]+=red[b][tid+s];
    }
    __syncthreads();
  }
  if (tid==0){
    float bs = ldin(bias,o,bf);
#pragma unroll
    for (int b=0;b<8;b++){
      float r = red[b][0]+bs;
      if (bf) ((bf16*)out)[b*40+o] = __float2bfloat16(r);
      else    ((float*)out)[b*40+o] = r;
    }
  }
}

extern "C" void kernel_launch(void* const* d_in, const int* in_sizes, int n_in,
                              void* d_out, int out_size, void* d_ws, size_t ws_size,
                              hipStream_t stream){
  const void* x    = d_in[0];
  const void* w00  = d_in[1];
  const void* g00  = d_in[2];
  const void* b00  = d_in[3];
  const void* w01  = d_in[4];
  const void* g01  = d_in[5];
  const void* b01  = d_in[6];
  const void* w1   = d_in[7];  const void* g1 = d_in[8];  const void* b1 = d_in[9];
  const void* w2   = d_in[10]; const void* g2 = d_in[11]; const void* b2 = d_in[12];
  const void* w3   = d_in[13]; const void* g3 = d_in[14]; const void* b3 = d_in[15];
  const void* w4   = d_in[16]; const void* g4 = d_in[17]; const void* b4 = d_in[18];
  const void* w5   = d_in[19]; const void* g5 = d_in[20]; const void* b5 = d_in[21];
  const void* w6   = d_in[22]; const void* g6 = d_in[23]; const void* b6 = d_in[24];
  const void* w7   = d_in[25]; const void* bias7 = d_in[26];
  const void* g7   = d_in[27]; const void* b7 = d_in[28];
  const void* w8   = d_in[29]; const void* bias8 = d_in[30];

  float* ws = (float*)d_ws;
  // workspace layout (float offsets)
  size_t o_xc0  = 0;                              // B*N*16
  size_t o_xcat = o_xc0  + (size_t)BB*NN*16;      // B*N*512
  size_t o_negd = o_xcat + (size_t)BB*NN*512;     // B*N*N (hmax/hmin overlay; h5)
  size_t o_u    = o_negd + (size_t)BB*NN*NN;      // B*N*256 dedicated
  size_t o_v    = o_u    + (size_t)BB*NN*256;     // B*N*256 dedicated
  size_t o_w1d  = o_v    + (size_t)BB*NN*256;     // 12*64
  size_t o_w1c  = o_w1d  + 12*64;
  size_t o_w2d  = o_w1c  + 12*64;                 // 64*64
  size_t o_w2c  = o_w2d  + 64*64;
  size_t o_w3d  = o_w2c  + 64*64;                 // 64*128
  size_t o_w3c  = o_w3d  + 64*128;
  size_t o_w4d  = o_w3c  + 64*128;                // 128*256
  size_t o_w4c  = o_w4d  + 128*256;
  size_t o_wb5  = o_w4c  + 128*256;               // 1024*512 bf16 = 262144 floats
  size_t o_st1  = o_wb5  + 262144;                // 8*2*64  = 1024 (zero region start)
  size_t o_st2  = o_st1  + 1024;                  // 8*2*64  = 1024
  size_t o_st3  = o_st2  + 1024;                  // 8*2*128 = 2048
  size_t o_st4  = o_st3  + 2048;                  // 8*2*256 = 4096
  size_t o_st5  = o_st4  + 4096;                  // 2048
  size_t o_pmax = o_st5  + 2048;                  // 8*1024 (uint)
  size_t o_psum = o_pmax + 8192;                  // 8*1024
  size_t o_cst  = o_psum + 8192;                  // 16 (conv0 stats)
  size_t o_xn4  = o_cst  + 16;                    // 8192 (atomic norms; zero region ends)
  size_t o_idx  = o_xn4  + 8192;                  // B*N*20 ints
  size_t o_y6   = o_idx  + (size_t)BB*NN*KK;      // 8*512
  size_t o_y7   = o_y6   + 4096;                  // 8*256
  size_t o_xn1  = o_y7   + 2048;                  // 8192 (direct-write norms)
  size_t o_xn2  = o_xn1  + 8192;                  // 8192
  size_t o_xn3  = o_xn2  + 8192;                  // 8192

  // overlays on the negD region (written only AFTER topk consumed negD):
  size_t o_hmax = o_negd;
  size_t o_hmin = o_negd + (size_t)2*BB*NN*256;
  size_t o_h5   = o_negd;                         // B*N*1024 bf16 (after eb4 apply)

  int* idxp = (int*)(ws + o_idx);
  float* negD = ws + o_negd;
  float* xc0  = ws + o_xc0;
  float* xcat = ws + o_xcat;
  float* up   = ws + o_u;
  float* vp   = ws + o_v;
  float* hxp  = ws + o_hmax;
  float* hnp  = ws + o_hmin;
  unsigned short* wb5 = (unsigned short*)(ws + o_wb5);
  unsigned short* h5b = (unsigned short*)(ws + o_h5);

  const int PREP_TOTAL = NZERO + 768 + 4096 + 8192 + 32768 + 1024*512;
  prep_kernel<<<(PREP_TOTAL+255)/256,256,0,stream>>>(
      x, w1,w2,w3,w4,w5, (unsigned*)(ws + o_st1),
      ws+o_w1d, ws+o_w1c, ws+o_w2d, ws+o_w2c,
      ws+o_w3d, ws+o_w3c, ws+o_w4d, ws+o_w4c, wb5);

  conv0_stats_kernel<<<32,256,0,stream>>>(x, w00, w01, ws+o_cst);
  conv0_apply_kernel<<<32,256,0,stream>>>(x, w00,g00,b00, w01,g01,b01, ws+o_cst,
                                          xc0, ws+o_xn1);

  dim3 kgrid(NN/128, NN/128, BB);               // 512 blocks
  const size_t KLDS16 = (2*128*16 + 256)*4;     // KCH=16
  const size_t KLDS64 = (2*128*64 + 256)*4;     // KCH=64
  const int TUVG = UVB + TKB;                   // uvgemm blocks FIRST, then topk

  // ---- edge block 1
  knndist_kernel<16,1><<<kgrid,512, KLDS16, stream>>>(xc0, 16, 0, ws+o_xn1, negD);
  topkuv_kernel<12,64><<<TUVG,256,0,stream>>>(negD, idxp, xc0, 16, 0,
      ws+o_w1d, ws+o_w1c, up, vp);
  ebgather_kernel<64><<<(BB*NN/4)*1,256,0,stream>>>(idxp, up, vp, hxp, hnp, ws+o_st1);
  ebapply_kernel<64,1><<<BB*NN*64/256,256,0,stream>>>(x, hxp, hnp, ws+o_st1, g1, b1,
      xcat, 0, ws+o_xn2);

  // ---- edge block 2
  knndist_kernel<64,1><<<kgrid,512, KLDS64, stream>>>(xcat, 512, 0, ws+o_xn2, negD);
  topkuv_kernel<64,64><<<TUVG,256,0,stream>>>(negD, idxp, xcat, 512, 0,
      ws+o_w2d, ws+o_w2c, up, vp);
  ebgather_kernel<64><<<(BB*NN/4)*1,256,0,stream>>>(idxp, up, vp, hxp, hnp, ws+o_st2);
  ebapply_kernel<64,1><<<BB*NN*64/256,256,0,stream>>>(x, hxp, hnp, ws+o_st2, g2, b2,
      xcat, 64, ws+o_xn3);

  // ---- edge block 3
  knndist_kernel<64,1><<<kgrid,512, KLDS64, stream>>>(xcat, 512, 64, ws+o_xn3, negD);
  topkuv_kernel<64,128><<<TUVG,256,0,stream>>>(negD, idxp, xcat, 512, 64,
      ws+o_w3d, ws+o_w3c, up, vp);
  ebgather_kernel<128><<<(BB*NN/4)*2,256,0,stream>>>(idxp, up, vp, hxp, hnp, ws+o_st3);
  ebapply_kernel<128,2><<<BB*NN*128/256,256,0,stream>>>(x, hxp, hnp, ws+o_st3, g3, b3,
      xcat, 128, ws+o_xn4);

  // ---- edge block 4
  knndist_kernel<64,2><<<kgrid,512, KLDS64, stream>>>(xcat, 512, 128, ws+o_xn4, negD);
  topkuv_kernel<128,256><<<TUVG,256,0,stream>>>(negD, idxp, xcat, 512, 128,
      ws+o_w4d, ws+o_w4c, up, vp);
  ebgather_kernel<256><<<(BB*NN/4)*4,256,0,stream>>>(idxp, up, vp, hxp, hnp, ws+o_st4);
  ebapply_kernel<256,0><<<BB*NN*256/256,256,0,stream>>>(x, hxp, hnp, ws+o_st4, g4, b4,
      xcat, 256, nullptr);

  // ---- conv5 MFMA (tiled GEMM) + pool
  fc5_mfma<<<dim3(8,64),256,0,stream>>>(xcat, wb5, ws+o_st5, h5b);
  pool5_kernel<<<BB*32,256,0,stream>>>(x, h5b, ws+o_st5, g5, b5,
                                       (unsigned*)(ws+o_pmax), ws+o_psum);

  // ---- FC head
  fc6_kernel<<<512,256,0,stream>>>(x, (unsigned*)(ws+o_pmax), ws+o_psum, w6, g6, b6, ws+o_y6);
  fc7_kernel<<<256,256,0,stream>>>(x, ws+o_y6, w7, bias7, g7, b7, ws+o_y7);
  fc8_kernel<<<40,256,0,stream>>>(x, ws+o_y7, w8, bias8, d_out);
}

// Round 20
// 555.799 us; speedup vs baseline: 1.0527x; 1.0527x over previous
//
#include <hip/hip_runtime.h>
#include <hip/hip_bf16.h>

#define BB 8
#define NN 1024
#define KK 20
#define EPSB 1e-5f

typedef __hip_bfloat16 bf16;
typedef __attribute__((ext_vector_type(8))) short sbf8;   // 8 bf16 = 4 VGPRs
typedef __attribute__((ext_vector_type(8))) unsigned short u16x8;
typedef __attribute__((ext_vector_type(4))) unsigned u32x4;
typedef __attribute__((ext_vector_type(4))) float f32x4;
typedef __attribute__((address_space(3))) unsigned lds_u32;
typedef const __attribute__((address_space(1))) unsigned glb_u32;

__device__ __forceinline__ float lrelu(float t){ return t >= 0.f ? t : 0.2f*t; }
__device__ __forceinline__ float ldin(const void* p, int i, int bf){
  return bf ? __bfloat162float(((const bf16*)p)[i]) : ((const float*)p)[i];
}
__device__ __forceinline__ unsigned short f2bf(float f){   // RNE fp32->bf16 bits
  unsigned u = __float_as_uint(f);
  return (unsigned short)((u + 0x7FFFu + ((u>>16)&1u)) >> 16);
}
__device__ __forceinline__ float bf2f(unsigned short us){
  return __uint_as_float((unsigned)us << 16);
}
__device__ __forceinline__ unsigned f2u_ord(float f){
  unsigned u = __float_as_uint(f);
  return (u & 0x80000000u) ? ~u : (u | 0x80000000u);
}
__device__ __forceinline__ float u2f_ord(unsigned u){
  return (u & 0x80000000u) ? __uint_as_float(u & 0x7fffffffu) : __uint_as_float(~u);
}
__device__ __forceinline__ unsigned umaxu(unsigned a, unsigned b){ return a > b ? a : b; }
__device__ __forceinline__ unsigned uminu(unsigned a, unsigned b){ return a < b ? a : b; }

// DPP-based wave64 reduce steps (VALU pipe, no LDS latency chain). HW-verified R4.
template<int CTRL>
__device__ __forceinline__ unsigned dppmax(unsigned x){
  unsigned y = (unsigned)__builtin_amdgcn_update_dpp((int)x, (int)x, CTRL, 0xF, 0xF, false);
  return x > y ? x : y;
}
template<int CTRL>
__device__ __forceinline__ unsigned dppmin(unsigned x){
  unsigned y = (unsigned)__builtin_amdgcn_update_dpp((int)x, (int)x, CTRL, 0xF, 0xF, false);
  return x < y ? x : y;
}

// inline dtype detect: full-wave ballot over x's first 64 words.
__device__ __forceinline__ int detect_bf(const void* x){
  unsigned w = ((const unsigned*)x)[threadIdx.x & 63];
  unsigned e = (w >> 23) & 0xFFu;
  unsigned long long m = __ballot(e >= 0xD0u);
  return (__popcll(m) >= 32) ? 1 : 0;
}

// ---------------- conv0 stats
__global__ __launch_bounds__(256) void conv0_stats_kernel(
    const void* __restrict__ x,
    const void* __restrict__ w00, const void* __restrict__ w01,
    float* __restrict__ cstat){
  const int bf = detect_bf(x);
  int i = blockIdx.x*256 + threadIdx.x;
  int b = i >> 10, n = i & 1023;
  float wz[4], wy[4];
#pragma unroll
  for (int j=0;j<4;j++){ wz[j]=ldin(w00,j,bf); wy[j]=ldin(w01,j,bf); }
  float x0 = ldin(x,(b*3+0)*NN + n,bf);
  float x1 = ldin(x,(b*3+1)*NN + n,bf);
  float x2 = ldin(x,(b*3+2)*NN + n,bf);
  float vals[6];
  vals[0] = wz[0]*x0 + wz[1]*x1;  vals[1] = wz[2]*x0 + wz[3]*x1;
  vals[2] = wy[0]*x0 + wy[1]*x2;  vals[3] = wy[2]*x0 + wy[3]*x2;
  vals[4] = wy[0]*x1 + wy[1]*x2;  vals[5] = wy[2]*x1 + wy[3]*x2;
  int lane = threadIdx.x & 63;
#pragma unroll
  for (int j=0;j<6;j++){
    float s1 = vals[j], s2 = vals[j]*vals[j];
#pragma unroll
    for (int off=32; off; off>>=1){
      s1 += __shfl_xor(s1, off, 64);
      s2 += __shfl_xor(s2, off, 64);
    }
    if (lane == 0){
      atomicAdd(&cstat[2*j], s1);
      atomicAdd(&cstat[2*j+1], s2);
    }
  }
}

// ---------------- conv0 apply: BN+lrelu+gate, writes xc0 rows + row norm (R12)
__global__ __launch_bounds__(256) void conv0_apply_kernel(
    const void* __restrict__ x,
    const void* __restrict__ w00, const void* __restrict__ g00, const void* __restrict__ b00,
    const void* __restrict__ w01, const void* __restrict__ g01, const void* __restrict__ b01,
    const float* __restrict__ cstat, float* __restrict__ xc0,
    float* __restrict__ xnorm){
  const int bf = detect_bf(x);
  int i = blockIdx.x*256 + threadIdx.x;
  int b = i >> 10, n = i & 1023;
  float wz[4], wy[4];
#pragma unroll
  for (int j=0;j<4;j++){ wz[j]=ldin(w00,j,bf); wy[j]=ldin(w01,j,bf); }
  float sA[6], sC[6];
#pragma unroll
  for (int j=0;j<6;j++){
    float m = cstat[2*j] * (1.f/(BB*NN));
    float v = cstat[2*j+1] * (1.f/(BB*NN)) - m*m;
    float g, bv;
    if (j<2){ g=ldin(g00,j,bf); bv=ldin(b00,j,bf); }
    else if (j<4){ g=ldin(g01,j-2,bf); bv=ldin(b01,j-2,bf); }
    else { g=ldin(g01,j-4,bf); bv=ldin(b01,j-4,bf); }
    float a = g * rsqrtf(fmaxf(v,0.f) + EPSB);
    sA[j]=a; sC[j]=bv - m*a;
  }
  float x0 = ldin(x,(b*3+0)*NN + n,bf);
  float x1 = ldin(x,(b*3+1)*NN + n,bf);
  float x2 = ldin(x,(b*3+2)*NN + n,bf);
  float z0 = wz[0]*x0 + wz[1]*x1, z1 = wz[2]*x0 + wz[3]*x1;
  float y0 = wy[0]*x0 + wy[1]*x2, y1 = wy[2]*x0 + wy[3]*x2;
  float u0 = wy[0]*x1 + wy[1]*x2, u1 = wy[2]*x1 + wy[3]*x2;
  float* row = xc0 + (size_t)i*16;
  float4 r0, r1, r2, r3;
  r0.x=x0; r0.y=x1; r0.z=x2;
  r0.w=lrelu(sA[4]*u0+sC[4])*x0;
  r1.x=lrelu(sA[5]*u1+sC[5])*x0;
  r1.y=lrelu(sA[2]*y0+sC[2])*x1;
  r1.z=lrelu(sA[3]*y1+sC[3])*x1;
  r1.w=lrelu(sA[0]*z0+sC[0])*x2;
  r2.x=lrelu(sA[1]*z1+sC[1])*x2;
  r2.y=0.f; r2.z=0.f; r2.w=0.f;
  r3.x=0.f; r3.y=0.f; r3.z=0.f; r3.w=0.f;
  *(float4*)&row[0]  = r0;
  *(float4*)&row[4]  = r1;
  *(float4*)&row[8]  = r2;
  *(float4*)&row[12] = r3;
  float nr = x0*x0 + x1*x1 + x2*x2
           + r0.w*r0.w + r1.x*r1.x + r1.y*r1.y + r1.z*r1.z + r1.w*r1.w
           + r2.x*r2.x;
  xnorm[i] = nr;
}

// ---------------- weight prep element
__device__ __forceinline__ void wuv_elem(const void* W, float* WdT, float* WcdT,
                                         int CIN, int COUT, int t, int bf){
  int c = t / COUT, o = t % COUT;
  if (c < CIN){
    float wd = ldin(W, o*(2*CIN)+c, bf);
    float wc = ldin(W, o*(2*CIN)+CIN+c, bf);
    WdT[t] = wd; WcdT[t] = wc - wd;
  } else {
    WdT[t] = 0.f; WcdT[t] = 0.f;
  }
}

// ---------------- fused prep
#define NZERO (1024+1024+2048+4096+2048+8192+8192+16+8192)
__global__ __launch_bounds__(256) void prep_kernel(
    const void* __restrict__ x,
    const void* __restrict__ w1, const void* __restrict__ w2,
    const void* __restrict__ w3, const void* __restrict__ w4,
    const void* __restrict__ w5,
    unsigned* __restrict__ zbase,
    float* __restrict__ w1d, float* __restrict__ w1c,
    float* __restrict__ w2d, float* __restrict__ w2c,
    float* __restrict__ w3d, float* __restrict__ w3c,
    float* __restrict__ w4d, float* __restrict__ w4c,
    unsigned short* __restrict__ wb5){
  const int bf = detect_bf(x);
  int t = blockIdx.x*256 + threadIdx.x;
  if (t < NZERO){ zbase[t] = 0u; return; }
  t -= NZERO;
  if (t < 768){ wuv_elem(w1, w1d, w1c, 9, 64, t, bf); return; }
  t -= 768;
  if (t < 4096){ wuv_elem(w2, w2d, w2c, 64, 64, t, bf); return; }
  t -= 4096;
  if (t < 8192){ wuv_elem(w3, w3d, w3c, 64, 128, t, bf); return; }
  t -= 8192;
  if (t < 32768){ wuv_elem(w4, w4d, w4c, 128, 256, t, bf); return; }
  t -= 32768;
  if (t < 1024*512) wb5[t] = f2bf(ldin(w5, t, bf));
}

// ---------------- fused negdist: 128x128 tiles, EXTERNAL row norms (R12-verified).
// 512 threads (R16: occupancy verified), R17 split store swizzle (R18-verified:
// knndist left top-5). Bitwise-identical negD.
template<int KCH, int NCH>
__global__ __launch_bounds__(512, 2) void knndist_kernel(
    const float* __restrict__ src, int ld, int coff,
    const float* __restrict__ xnorm, float* __restrict__ negD){
  constexpr int NG = KCH >> 2;
  constexpr int GM = NG - 1;
  extern __shared__ float lds[];
  float* At = lds;
  float* Bt = lds + 128*KCH;
  float* xn = Bt + 128*KCH;
  int b = blockIdx.z, i0 = blockIdx.y*128, j0 = blockIdx.x*128;
  int tid = threadIdx.x;
  int ti = tid >> 4, tj = tid & 15;
  int gsa = ti & GM;                       // At store is (r>>2)&GM
  int gsb = tj & GM;                       // Bt store is (r>>3)&GM
  if (tid < 256)
    xn[tid] = xnorm[(size_t)b*NN + (tid < 128 ? i0 + tid : j0 + tid - 128)];
  float acc[4][8];
#pragma unroll
  for (int u=0;u<4;u++)
#pragma unroll
    for (int v=0;v<8;v++) acc[u][v]=0.f;
#pragma unroll 1
  for (int ch=0; ch<NCH; ch++){
    int c0 = ch*KCH;
    __syncthreads();
#pragma unroll
    for (int it=0; it<(2*128*NG)/512; it++){
      int t = it*512 + tid;
      int half = (t >= 128*NG);
      int tt = half ? t - 128*NG : t;
      int r = tt / NG, g = tt % NG;
      int base = half ? j0 : i0;
      float4 f = *(const float4*)&src[(size_t)(b*NN + base + r)*ld + coff + c0 + g*4];
      int gs = g ^ (half ? ((r>>3) & GM) : ((r>>2) & GM));
      float* dst = (half ? Bt : At) + r*KCH + gs*4;
      *(float4*)dst = f;
    }
    __syncthreads();
#pragma unroll 2
    for (int g=0; g<NG; g++){
      float4 av[4];
#pragma unroll
      for (int u=0;u<4;u++)
        av[u] = *(const float4*)&At[(ti*4+u)*KCH + ((g ^ gsa)<<2)];
#pragma unroll
      for (int v=0;v<8;v++){
        float4 bv = *(const float4*)&Bt[(tj*8+v)*KCH + ((g ^ gsb)<<2)];
#pragma unroll
        for (int u=0;u<4;u++)
          acc[u][v] += av[u].x*bv.x + av[u].y*bv.y + av[u].z*bv.z + av[u].w*bv.w;
      }
    }
  }
  float xi[4], xj[8];
#pragma unroll
  for (int u=0;u<4;u++) xi[u] = xn[ti*4+u];
#pragma unroll
  for (int v=0;v<8;v++) xj[v] = xn[128 + tj*8+v];
#pragma unroll
  for (int u=0;u<4;u++){
    float* orow = &negD[((size_t)(b*NN + i0 + ti*4 + u))*NN + j0 + tj*8];
#pragma unroll
    for (int vg=0; vg<2; vg++){
      float4 ov;
      ov.x = 2.f*acc[u][vg*4+0] - xi[u] - xj[vg*4+0];
      ov.y = 2.f*acc[u][vg*4+1] - xi[u] - xj[vg*4+1];
      ov.z = 2.f*acc[u][vg*4+2] - xi[u] - xj[vg*4+2];
      ov.w = 2.f*acc[u][vg*4+3] - xi[u] - xj[vg*4+3];
      *(float4*)&orow[vg*4] = ov;
    }
  }
}

// ---------------- fused u/v GEMM + top-20 (uvgemm first; R5-verified).
// R20: topk reverted to R18 single-row (R19 2-row interleave regressed: VGPR
// 64->44 = compiler spill/restructure; topk is ISSUE-bound at 75% VALUBusy,
// so cut INSTRUCTIONS instead). New: ballot fast-path replaces the min-index
// DPP chain when the round's max is unique (ballot popc==1 -> readlane g1 from
// that lane; within-lane first-occurrence is already min-index since the s-scan
// is monotone in global index). Exact-tie fallback = old min-reduce, bit-exact.
#define UVB 1024     // uvgemm blocks = 8192/PT
template<int CINP,int COUT>
__global__ __launch_bounds__(256, 4) void topkuv_kernel(
    const float* __restrict__ negD, int* __restrict__ idx,
    const float* __restrict__ srcT, int ld, int coff,
    const float* __restrict__ WdT, const float* __restrict__ WcdT,
    float* __restrict__ ut, float* __restrict__ vt){
  constexpr int PT = 8;
  __shared__ float xs[PT*CINP];
  int tid = threadIdx.x;
  if (blockIdx.x < UVB){
    constexpr int G = 256/COUT, NP = PT/G;
    int base = blockIdx.x*PT;
    for (int t=tid; t<PT*CINP; t+=256){
      int p = t / CINP, c = t % CINP;
      xs[t] = srcT[(size_t)(base+p)*ld + coff + c];
    }
    __syncthreads();
    int o = tid % COUT, grp = tid / COUT;
    float u[NP], v[NP];
#pragma unroll
    for (int pp=0;pp<NP;pp++){ u[pp]=0.f; v[pp]=0.f; }
    for (int c=0;c<CINP;c+=4){
      float wd0 = WdT[(c+0)*COUT+o], wc0 = WcdT[(c+0)*COUT+o];
      float wd1 = WdT[(c+1)*COUT+o], wc1 = WcdT[(c+1)*COUT+o];
      float wd2 = WdT[(c+2)*COUT+o], wc2 = WcdT[(c+2)*COUT+o];
      float wd3 = WdT[(c+3)*COUT+o], wc3 = WcdT[(c+3)*COUT+o];
#pragma unroll
      for (int pp=0;pp<NP;pp++){
        float4 xv = *(const float4*)&xs[(grp+pp*G)*CINP + c];
        u[pp] = fmaf(xv.x,wd0,fmaf(xv.y,wd1,fmaf(xv.z,wd2,fmaf(xv.w,wd3,u[pp]))));
        v[pp] = fmaf(xv.x,wc0,fmaf(xv.y,wc1,fmaf(xv.z,wc2,fmaf(xv.w,wc3,v[pp]))));
      }
    }
#pragma unroll
    for (int pp=0;pp<NP;pp++){
      int p = grp + pp*G;
      ut[(size_t)(base+p)*COUT + o] = u[pp];
      vt[(size_t)(base+p)*COUT + o] = v[pp];
    }
    return;
  }
  // ---------- topk (DPP max reduce + top-2 lane cache + ballot fast-path)
  int row_id = ((blockIdx.x - UVB)*256 + tid) >> 6;
  int lane = tid & 63;
  const float* row = negD + (size_t)row_id*NN;
  unsigned kv[16];
#pragma unroll
  for (int j=0;j<4;j++){
    float4 f = *(const float4*)&row[j*256 + lane*4];
    kv[j*4+0]=f2u_ord(f.x); kv[j*4+1]=f2u_ord(f.y);
    kv[j*4+2]=f2u_ord(f.z); kv[j*4+3]=f2u_ord(f.w);
  }
  const unsigned lane4 = (unsigned)(lane << 2);
  unsigned v1=0u, g1=0u, v2=0u, g2=0u;
#pragma unroll
  for (int s=0;s<16;s++){
    unsigned go = lane4 + (unsigned)(((s>>2)<<8) + (s&3));
    bool gt1 = kv[s] > v1, gt2 = kv[s] > v2;
    v2 = gt1 ? v1 : (gt2 ? kv[s] : v2);
    g2 = gt1 ? g1 : (gt2 ? go    : g2);
    v1 = gt1 ? kv[s] : v1;
    g1 = gt1 ? go    : g1;
  }
  unsigned consumed = 0u;
  int myidx = 0;
  int* orow = idx + (size_t)row_id*KK;
#pragma unroll 1
  for (int k=0;k<KK;k++){
    // wave max of v1
    unsigned m = v1;
    m = dppmax<0xB1>(m);
    m = dppmax<0x4E>(m);
    m = dppmax<0x124>(m);
    m = dppmax<0x128>(m);
    unsigned w0 = (unsigned)__builtin_amdgcn_readlane((int)m, 0);
    unsigned w1 = (unsigned)__builtin_amdgcn_readlane((int)m, 16);
    unsigned w2 = (unsigned)__builtin_amdgcn_readlane((int)m, 32);
    unsigned w3 = (unsigned)__builtin_amdgcn_readlane((int)m, 48);
    unsigned win = umaxu(umaxu(w0,w1), umaxu(w2,w3));
    // winner index: ballot fast-path (unique max lane), exact-tie fallback
    unsigned long long msk = __ballot(v1 == win);
    unsigned widx;
    if (__popcll(msk) == 1){
      int ln = (int)(__ffsll(msk) - 1);                    // wave-uniform SGPR
      widx = (unsigned)__builtin_amdgcn_readlane((int)g1, ln);
    } else {
      unsigned c = (v1 == win) ? g1 : 0xFFFFFFFFu;
      c = dppmin<0xB1>(c);
      c = dppmin<0x4E>(c);
      c = dppmin<0x124>(c);
      c = dppmin<0x128>(c);
      unsigned c0 = (unsigned)__builtin_amdgcn_readlane((int)c, 0);
      unsigned c1 = (unsigned)__builtin_amdgcn_readlane((int)c, 16);
      unsigned c2 = (unsigned)__builtin_amdgcn_readlane((int)c, 32);
      unsigned c3 = (unsigned)__builtin_amdgcn_readlane((int)c, 48);
      widx = uminu(uminu(c0,c1), uminu(c2,c3));
    }
    myidx = (lane == k) ? (int)widx : myidx;       // round-k result kept by lane k
    bool mine = (g1 == widx);                      // g values are unique per lane
    bool rf = mine && (v2 == 0u);                  // cache will be empty -> refill
    v1 = mine ? v2 : v1;
    g1 = mine ? g2 : g1;
    v2 = mine ? 0u : v2;
    unsigned slot = ((widx >> 8) << 2) | (widx & 3u);
    consumed |= (mine ? (1u << slot) : 0u);
    if (__ballot(rf)){                             // rare, wave-uniform branch
      unsigned nv1=0u, ng1=0u, nv2=0u, ng2=0u;
#pragma unroll
      for (int s=0;s<16;s++){
        unsigned go = lane4 + (unsigned)(((s>>2)<<8) + (s&3));
        unsigned val = (consumed & (1u<<s)) ? 0u : kv[s];
        bool gt1 = val > nv1, gt2 = val > nv2;
        nv2 = gt1 ? nv1 : (gt2 ? val : nv2);
        ng2 = gt1 ? ng1 : (gt2 ? go  : ng2);
        nv1 = gt1 ? val : nv1;
        ng1 = gt1 ? go  : ng1;
      }
      v1 = rf ? nv1 : v1;  g1 = rf ? ng1 : g1;
      v2 = rf ? nv2 : v2;  g2 = rf ? ng2 : g2;
    }
  }
  if (lane < KK) orow[lane] = myidx;
}

// ---------------- gather (R8 DMA + R10 per-batch stats; both verified)
template<int COUT>
__global__ __launch_bounds__(256, 4) void ebgather_kernel(
    const int* __restrict__ idx, const float* __restrict__ ut, const float* __restrict__ vt,
    float* __restrict__ hmaxb, float* __restrict__ hminb, float* __restrict__ stats){
  constexpr int CHG = COUT/64;
  __shared__ float sred[128];
  __shared__ float hstage[4*KK*64];
  int w = threadIdx.x >> 6, lane = threadIdx.x & 63;
  int pb  = blockIdx.x / CHG;
  int chg = blockIdx.x % CHG;
  int nu = __builtin_amdgcn_readfirstlane(pb*4 + w);
  int b = nu >> 10;
  int bblk = (pb*4) >> 10;
  if (threadIdx.x < 128) sred[threadIdx.x] = 0.f;
  __syncthreads();
  const int* irow = idx + (size_t)nu*KK;
  int m[KK];
#pragma unroll
  for (int k=0;k<KK;k++) m[k] = __builtin_amdgcn_readfirstlane(irow[k]);
  int co = chg*64 + lane;
  float vr = vt[(size_t)nu*COUT + co];
  float* hbase = &hstage[w*KK*64];
#pragma unroll
  for (int k=0;k<KK;k++){
    const float* src = &ut[(size_t)(b*NN + m[k])*COUT + co];
    __builtin_amdgcn_global_load_lds((glb_u32*)src, (lds_u32*)&hbase[k*64], 4, 0, 0);
  }
  asm volatile("s_waitcnt vmcnt(0)" ::: "memory");
  float hx=-1e30f, hn=1e30f, s1=0.f, s2=0.f;
#pragma unroll
  for (int k=0;k<KK;k++){
    float t = hbase[k*64 + lane] + vr;
    hx = fmaxf(hx, t);
    hn = fminf(hn, t);
    s1 += t;
    s2 = fmaf(t, t, s2);
  }
  hmaxb[(size_t)nu*COUT + co] = hx;
  hminb[(size_t)nu*COUT + co] = hn;
  atomicAdd(&sred[lane], s1);
  atomicAdd(&sred[64+lane], s2);
  __syncthreads();
  if (threadIdx.x < 128){
    int which = threadIdx.x >> 6, l = threadIdx.x & 63;
    atomicAdd(&stats[(size_t)bblk*2*COUT + which*COUT + chg*64 + l],
              sred[which*64 + l]);
  }
}

// ---------------- apply (per-batch stat partials; emits norms for next knndist)
template<int COUT, int NORMMODE>
__global__ __launch_bounds__(256) void ebapply_kernel(
    const void* __restrict__ x,
    const float* __restrict__ hmaxb, const float* __restrict__ hminb,
    const float* __restrict__ stats, const void* __restrict__ g, const void* __restrict__ bb,
    float* __restrict__ outp, int outoff, float* __restrict__ xnorm){
  const int bf = detect_bf(x);
  int t = blockIdx.x*256 + threadIdx.x;
  int n = t / COUT, o = t % COUT;
  const float inv_count = 1.f/(BB*NN*KK);
  float s1 = 0.f, s2 = 0.f;
#pragma unroll
  for (int p=0;p<BB;p++){
    s1 += stats[(size_t)p*2*COUT + o];
    s2 += stats[(size_t)p*2*COUT + COUT + o];
  }
  float m = s1*inv_count;
  float var = s2*inv_count - m*m;
  float a = ldin(g,o,bf)*rsqrtf(fmaxf(var,0.f) + EPSB);
  float c = ldin(bb,o,bf) - m*a;
  float h = (a >= 0.f) ? hmaxb[t] : hminb[t];
  float r = lrelu(fmaf(a,h,c));
  outp[(size_t)n*512 + outoff + o] = r;
  if (NORMMODE){
    float s = r*r;
#pragma unroll
    for (int off=32; off; off>>=1) s += __shfl_xor(s, off, 64);
    int lane = threadIdx.x & 63;
    if (NORMMODE == 1){ if (lane == 0) xnorm[n] = s; }
    else              { if (lane == 0) atomicAdd(&xnorm[n], s); }
  }
}

// ---------------- conv5 via MFMA bf16 — 128x128x64 tiled GEMM (R1-verified).
__global__ __launch_bounds__(256) void fc5_mfma(
    const float* __restrict__ xcat, const unsigned short* __restrict__ wb5,
    float* __restrict__ st5, unsigned short* __restrict__ hbufb){
  __shared__ unsigned As[128*32];
  __shared__ unsigned Bs[128*32];
  int tid = threadIdx.x;
  int n0 = blockIdx.x * 128;
  int m0 = blockIdx.y * 128;
  int lane = tid & 63, w = tid >> 6;
  int wr = w >> 1, wc = w & 1;
  int col = lane & 15, quad = lane >> 4;

  int r0 = tid >> 3, g0 = tid & 7;
  int gsw = g0 ^ (r0 & 7);

  float4  arA[4][2];
  u16x8   brB[4];

  auto load_regs = [&](int k0){
#pragma unroll
    for (int j=0;j<4;j++){
      const float* ap = xcat + (size_t)(m0 + j*32 + r0)*512 + k0 + gsw*8;
      arA[j][0] = *(const float4*)ap;
      arA[j][1] = *(const float4*)(ap + 4);
      brB[j] = *(const u16x8*)(wb5 + (size_t)(n0 + j*32 + r0)*512 + k0 + gsw*8);
    }
  };

  f32x4 acc[4][4];
#pragma unroll
  for (int mi=0;mi<4;mi++)
#pragma unroll
    for (int ni=0;ni<4;ni++) acc[mi][ni] = (f32x4){0.f,0.f,0.f,0.f};

  load_regs(0);
  for (int ks=0; ks<8; ks++){
    __syncthreads();
#pragma unroll
    for (int j=0;j<4;j++){
      u32x4 pk;
      pk.x = (unsigned)f2bf(arA[j][0].x) | ((unsigned)f2bf(arA[j][0].y) << 16);
      pk.y = (unsigned)f2bf(arA[j][0].z) | ((unsigned)f2bf(arA[j][0].w) << 16);
      pk.z = (unsigned)f2bf(arA[j][1].x) | ((unsigned)f2bf(arA[j][1].y) << 16);
      pk.w = (unsigned)f2bf(arA[j][1].z) | ((unsigned)f2bf(arA[j][1].w) << 16);
      *(u32x4*)&As[(j*256 + tid)*4] = pk;
      *(u16x8*)&Bs[(j*256 + tid)*4] = brB[j];
    }
    if (ks < 7) load_regs((ks+1)*64);
    __syncthreads();
#pragma unroll
    for (int kf=0; kf<2; kf++){
      int G = kf*4 + quad;
      sbf8 af[4], bfr[4];
#pragma unroll
      for (int mi=0;mi<4;mi++){
        int rr = wr*64 + mi*16 + col;
        af[mi] = *(const sbf8*)&As[rr*32 + ((G ^ (rr&7))<<2)];
      }
#pragma unroll
      for (int ni=0;ni<4;ni++){
        int rr = wc*64 + ni*16 + col;
        bfr[ni] = *(const sbf8*)&Bs[rr*32 + ((G ^ (rr&7))<<2)];
      }
#pragma unroll
      for (int mi=0;mi<4;mi++)
#pragma unroll
        for (int ni=0;ni<4;ni++)
          acc[mi][ni] = __builtin_amdgcn_mfma_f32_16x16x32_bf16(
              af[mi], bfr[ni], acc[mi][ni], 0, 0, 0);
    }
  }

#pragma unroll
  for (int ni=0;ni<4;ni++){
    float s1 = 0.f, s2 = 0.f;
#pragma unroll
    for (int mi=0;mi<4;mi++){
      f32x4 a = acc[mi][ni];
      s1 += a.x + a.y + a.z + a.w;
      s2 += a.x*a.x + a.y*a.y + a.z*a.z + a.w*a.w;
    }
    s1 += __shfl_xor(s1,16,64); s2 += __shfl_xor(s2,16,64);
    s1 += __shfl_xor(s1,32,64); s2 += __shfl_xor(s2,32,64);
    if (lane < 16){
      int o = n0 + wc*64 + ni*16 + lane;
      atomicAdd(&st5[o], s1);
      atomicAdd(&st5[1024+o], s2);
    }
  }
#pragma unroll
  for (int mi=0;mi<4;mi++){
    int row = m0 + wr*64 + mi*16 + quad*4;
#pragma unroll
    for (int ni=0;ni<4;ni++){
      int o = n0 + wc*64 + ni*16 + col;
      f32x4 a = acc[mi][ni];
      unsigned short* hp = hbufb + (size_t)row*1024 + o;
      hp[0]      = f2bf(a.x);
      hp[1024]   = f2bf(a.y);
      hp[2*1024] = f2bf(a.z);
      hp[3*1024] = f2bf(a.w);
    }
  }
}

// ---------------- pool over n
__global__ __launch_bounds__(256) void pool5_kernel(
    const void* __restrict__ x,
    const unsigned short* __restrict__ hbufb, const float* __restrict__ st5,
    const void* __restrict__ g5, const void* __restrict__ b5,
    unsigned* __restrict__ pmax, float* __restrict__ psum){
  const int bf = detect_bf(x);
  int b = blockIdx.x >> 5;
  int ns = blockIdx.x & 31;
  int o4 = threadIdx.x*4;
  const float inv_count = 1.f/(BB*NN);
  float a[4], c[4];
#pragma unroll
  for (int j=0;j<4;j++){
    int o = o4+j;
    float m = st5[o]*inv_count;
    float var = st5[1024+o]*inv_count - m*m;
    a[j] = ldin(g5,o,bf)*rsqrtf(fmaxf(var,0.f)+EPSB);
    c[j] = ldin(b5,o,bf) - m*a[j];
  }
  float mx0=-1e30f,mx1=-1e30f,mx2=-1e30f,mx3=-1e30f;
  float sm0=0.f,sm1=0.f,sm2=0.f,sm3=0.f;
  for (int n = ns*32; n < ns*32+32; n++){
    ushort4 hu = *(const ushort4*)&hbufb[(size_t)(b*NN + n)*1024 + o4];
    float t0 = lrelu(fmaf(a[0],bf2f(hu.x),c[0]));
    float t1 = lrelu(fmaf(a[1],bf2f(hu.y),c[1]));
    float t2 = lrelu(fmaf(a[2],bf2f(hu.z),c[2]));
    float t3 = lrelu(fmaf(a[3],bf2f(hu.w),c[3]));
    mx0=fmaxf(mx0,t0); mx1=fmaxf(mx1,t1); mx2=fmaxf(mx2,t2); mx3=fmaxf(mx3,t3);
    sm0+=t0; sm1+=t1; sm2+=t2; sm3+=t3;
  }
  atomicMax(&pmax[b*1024+o4+0], f2u_ord(mx0));
  atomicMax(&pmax[b*1024+o4+1], f2u_ord(mx1));
  atomicMax(&pmax[b*1024+o4+2], f2u_ord(mx2));
  atomicMax(&pmax[b*1024+o4+3], f2u_ord(mx3));
  atomicAdd(&psum[b*1024+o4+0], sm0);
  atomicAdd(&psum[b*1024+o4+1], sm1);
  atomicAdd(&psum[b*1024+o4+2], sm2);
  atomicAdd(&psum[b*1024+o4+3], sm3);
}

// ---------------- FC head
__global__ __launch_bounds__(256) void fc6_kernel(
    const void* __restrict__ x,
    const unsigned* __restrict__ pmax, const float* __restrict__ psum,
    const void* __restrict__ W,
    const void* __restrict__ g, const void* __restrict__ bb, float* __restrict__ y6){
  __shared__ float red[8][256];
  int o = blockIdx.x, tid = threadIdx.x;
  const int bf = detect_bf(x);
  float part[8];
#pragma unroll
  for (int b=0;b<8;b++) part[b]=0.f;
  for (int c=tid;c<2048;c+=256){
    float wv = ldin(W,o*2048+c,bf);
#pragma unroll
    for (int b=0;b<8;b++){
      float pv = (c < 1024) ? u2f_ord(pmax[b*1024+c])
                            : psum[b*1024 + (c-1024)] * (1.f/1024.f);
      part[b] = fmaf(pv, wv, part[b]);
    }
  }
#pragma unroll
  for (int b=0;b<8;b++) red[b][tid]=part[b];
  __syncthreads();
  for (int s=128;s;s>>=1){
    if (tid<s){
#pragma unroll
      for (int b=0;b<8;b++) red[b][tid]+=red[b][tid+s];
    }
    __syncthreads();
  }
  if (tid==0){
    float y[8], m=0.f;
#pragma unroll
    for (int b=0;b<8;b++){ y[b]=red[b][0]; m+=y[b]; }
    m *= 0.125f;
    float v=0.f;
#pragma unroll
    for (int b=0;b<8;b++){ float d=y[b]-m; v += d*d; }
    v *= 0.125f;
    float a=ldin(g,o,bf)*rsqrtf(fmaxf(v,0.f)+EPSB), c0=ldin(bb,o,bf)-m*a;
#pragma unroll
    for (int b=0;b<8;b++) y6[b*512+o]=lrelu(fmaf(a,y[b],c0));
  }
}

__global__ __launch_bounds__(256) void fc7_kernel(
    const void* __restrict__ x,
    const float* __restrict__ y6, const void* __restrict__ W, const void* __restrict__ bias,
    const void* __restrict__ g, const void* __restrict__ bb, float* __restrict__ y7){
  __shared__ float red[8][256];
  int o = blockIdx.x, tid = threadIdx.x;
  const int bf = detect_bf(x);
  float part[8];
#pragma unroll
  for (int b=0;b<8;b++) part[b]=0.f;
  for (int c=tid;c<512;c+=256){
    float wv = ldin(W,o*512+c,bf);
#pragma unroll
    for (int b=0;b<8;b++) part[b] = fmaf(y6[b*512+c], wv, part[b]);
  }
#pragma unroll
  for (int b=0;b<8;b++) red[b][tid]=part[b];
  __syncthreads();
  for (int s=128;s;s>>=1){
    if (tid<s){
#pragma unroll
      for (int b=0;b<8;b++) red[b][tid]+=red[b][tid+s];
    }
    __syncthreads();
  }
  if (tid==0){
    float bs = ldin(bias,o,bf);
    float y[8], m=0.f;
#pragma unroll
    for (int b=0;b<8;b++){ y[b]=red[b][0]+bs; m+=y[b]; }
    m *= 0.125f;
    float v=0.f;
#pragma unroll
    for (int b=0;b<8;b++){ float d=y[b]-m; v += d*d; }
    v *= 0.125f;
    float a=ldin(g,o,bf)*rsqrtf(fmaxf(v,0.f)+EPSB), c0=ldin(bb,o,bf)-m*a;
#pragma unroll
    for (int b=0;b<8;b++) y7[b*256+o]=lrelu(fmaf(a,y[b],c0));
  }
}

__global__ __launch_bounds__(256) void fc8_kernel(
    const void* __restrict__ x,
    const float* __restrict__ y7, const void* __restrict__ W, const void* __restrict__ bias,
    void* __restrict__ out){
  __shared__ float red[8][256];
  int o = blockIdx.x, tid = threadIdx.x;
  const int bf = detect_bf(x);
  float wv = ldin(W,o*256+tid,bf);
#pragma unroll
  for (int b=0;b<8;b++) red[b][tid] = y7[b*256+tid]*wv;
  __syncthreads();
  for (int s=128;s;s>>=1){
    if (tid<s){
#pragma unroll
      for (int b=0;b<8;b++) red[b][tid]+=red[b][tid+s];
    }
    __syncthreads();
  }
  if (tid==0){
    float bs = ldin(bias,o,bf);
#pragma unroll
    for (int b=0;b<8;b++){
      float r = red[b][0]+bs;
      if (bf) ((bf16*)out)[b*40+o] = __float2bfloat16(r);
      else    ((float*)out)[b*40+o] = r;
    }
  }
}

extern "C" void kernel_launch(void* const* d_in, const int* in_sizes, int n_in,
                              void* d_out, int out_size, void* d_ws, size_t ws_size,
                              hipStream_t stream){
  const void* x    = d_in[0];
  const void* w00  = d_in[1];
  const void* g00  = d_in[2];
  const void* b00  = d_in[3];
  const void* w01  = d_in[4];
  const void* g01  = d_in[5];
  const void* b01  = d_in[6];
  const void* w1   = d_in[7];  const void* g1 = d_in[8];  const void* b1 = d_in[9];
  const void* w2   = d_in[10]; const void* g2 = d_in[11]; const void* b2 = d_in[12];
  const void* w3   = d_in[13]; const void* g3 = d_in[14]; const void* b3 = d_in[15];
  const void* w4   = d_in[16]; const void* g4 = d_in[17]; const void* b4 = d_in[18];
  const void* w5   = d_in[19]; const void* g5 = d_in[20]; const void* b5 = d_in[21];
  const void* w6   = d_in[22]; const void* g6 = d_in[23]; const void* b6 = d_in[24];
  const void* w7   = d_in[25]; const void* bias7 = d_in[26];
  const void* g7   = d_in[27]; const void* b7 = d_in[28];
  const void* w8   = d_in[29]; const void* bias8 = d_in[30];

  float* ws = (float*)d_ws;
  // workspace layout (float offsets)
  size_t o_xc0  = 0;                              // B*N*16
  size_t o_xcat = o_xc0  + (size_t)BB*NN*16;      // B*N*512
  size_t o_negd = o_xcat + (size_t)BB*NN*512;     // B*N*N (hmax/hmin overlay; h5)
  size_t o_u    = o_negd + (size_t)BB*NN*NN;      // B*N*256 dedicated
  size_t o_v    = o_u    + (size_t)BB*NN*256;     // B*N*256 dedicated
  size_t o_w1d  = o_v    + (size_t)BB*NN*256;     // 12*64
  size_t o_w1c  = o_w1d  + 12*64;
  size_t o_w2d  = o_w1c  + 12*64;                 // 64*64
  size_t o_w2c  = o_w2d  + 64*64;
  size_t o_w3d  = o_w2c  + 64*64;                 // 64*128
  size_t o_w3c  = o_w3d  + 64*128;
  size_t o_w4d  = o_w3c  + 64*128;                // 128*256
  size_t o_w4c  = o_w4d  + 128*256;
  size_t o_wb5  = o_w4c  + 128*256;               // 1024*512 bf16 = 262144 floats
  size_t o_st1  = o_wb5  + 262144;                // 8*2*64  = 1024 (zero region start)
  size_t o_st2  = o_st1  + 1024;                  // 8*2*64  = 1024
  size_t o_st3  = o_st2  + 1024;                  // 8*2*128 = 2048
  size_t o_st4  = o_st3  + 2048;                  // 8*2*256 = 4096
  size_t o_st5  = o_st4  + 4096;                  // 2048
  size_t o_pmax = o_st5  + 2048;                  // 8*1024 (uint)
  size_t o_psum = o_pmax + 8192;                  // 8*1024
  size_t o_cst  = o_psum + 8192;                  // 16 (conv0 stats)
  size_t o_xn4  = o_cst  + 16;                    // 8192 (atomic norms; zero region ends)
  size_t o_idx  = o_xn4  + 8192;                  // B*N*20 ints
  size_t o_y6   = o_idx  + (size_t)BB*NN*KK;      // 8*512
  size_t o_y7   = o_y6   + 4096;                  // 8*256
  size_t o_xn1  = o_y7   + 2048;                  // 8192 (direct-write norms)
  size_t o_xn2  = o_xn1  + 8192;                  // 8192
  size_t o_xn3  = o_xn2  + 8192;                  // 8192

  // overlays on the negD region (written only AFTER topk consumed negD):
  size_t o_hmax = o_negd;
  size_t o_hmin = o_negd + (size_t)2*BB*NN*256;
  size_t o_h5   = o_negd;                         // B*N*1024 bf16 (after eb4 apply)

  int* idxp = (int*)(ws + o_idx);
  float* negD = ws + o_negd;
  float* xc0  = ws + o_xc0;
  float* xcat = ws + o_xcat;
  float* up   = ws + o_u;
  float* vp   = ws + o_v;
  float* hxp  = ws + o_hmax;
  float* hnp  = ws + o_hmin;
  unsigned short* wb5 = (unsigned short*)(ws + o_wb5);
  unsigned short* h5b = (unsigned short*)(ws + o_h5);

  const int PREP_TOTAL = NZERO + 768 + 4096 + 8192 + 32768 + 1024*512;
  prep_kernel<<<(PREP_TOTAL+255)/256,256,0,stream>>>(
      x, w1,w2,w3,w4,w5, (unsigned*)(ws + o_st1),
      ws+o_w1d, ws+o_w1c, ws+o_w2d, ws+o_w2c,
      ws+o_w3d, ws+o_w3c, ws+o_w4d, ws+o_w4c, wb5);

  conv0_stats_kernel<<<32,256,0,stream>>>(x, w00, w01, ws+o_cst);
  conv0_apply_kernel<<<32,256,0,stream>>>(x, w00,g00,b00, w01,g01,b01, ws+o_cst,
                                          xc0, ws+o_xn1);

  dim3 kgrid(NN/128, NN/128, BB);               // 512 blocks
  const size_t KLDS16 = (2*128*16 + 256)*4;     // KCH=16
  const size_t KLDS64 = (2*128*64 + 256)*4;     // KCH=64
  const int TUVG = UVB + 2048;                  // uvgemm blocks FIRST, then topk

  // ---- edge block 1
  knndist_kernel<16,1><<<kgrid,512, KLDS16, stream>>>(xc0, 16, 0, ws+o_xn1, negD);
  topkuv_kernel<12,64><<<TUVG,256,0,stream>>>(negD, idxp, xc0, 16, 0,
      ws+o_w1d, ws+o_w1c, up, vp);
  ebgather_kernel<64><<<(BB*NN/4)*1,256,0,stream>>>(idxp, up, vp, hxp, hnp, ws+o_st1);
  ebapply_kernel<64,1><<<BB*NN*64/256,256,0,stream>>>(x, hxp, hnp, ws+o_st1, g1, b1,
      xcat, 0, ws+o_xn2);

  // ---- edge block 2
  knndist_kernel<64,1><<<kgrid,512, KLDS64, stream>>>(xcat, 512, 0, ws+o_xn2, negD);
  topkuv_kernel<64,64><<<TUVG,256,0,stream>>>(negD, idxp, xcat, 512, 0,
      ws+o_w2d, ws+o_w2c, up, vp);
  ebgather_kernel<64><<<(BB*NN/4)*1,256,0,stream>>>(idxp, up, vp, hxp, hnp, ws+o_st2);
  ebapply_kernel<64,1><<<BB*NN*64/256,256,0,stream>>>(x, hxp, hnp, ws+o_st2, g2, b2,
      xcat, 64, ws+o_xn3);

  // ---- edge block 3
  knndist_kernel<64,1><<<kgrid,512, KLDS64, stream>>>(xcat, 512, 64, ws+o_xn3, negD);
  topkuv_kernel<64,128><<<TUVG,256,0,stream>>>(negD, idxp, xcat, 512, 64,
      ws+o_w3d, ws+o_w3c, up, vp);
  ebgather_kernel<128><<<(BB*NN/4)*2,256,0,stream>>>(idxp, up, vp, hxp, hnp, ws+o_st3);
  ebapply_kernel<128,2><<<BB*NN*128/256,256,0,stream>>>(x, hxp, hnp, ws+o_st3, g3, b3,
      xcat, 128, ws+o_xn4);

  // ---- edge block 4
  knndist_kernel<64,2><<<kgrid,512, KLDS64, stream>>>(xcat, 512, 128, ws+o_xn4, negD);
  topkuv_kernel<128,256><<<TUVG,256,0,stream>>>(negD, idxp, xcat, 512, 128,
      ws+o_w4d, ws+o_w4c, up, vp);
  ebgather_kernel<256><<<(BB*NN/4)*4,256,0,stream>>>(idxp, up, vp, hxp, hnp, ws+o_st4);
  ebapply_kernel<256,0><<<BB*NN*256/256,256,0,stream>>>(x, hxp, hnp, ws+o_st4, g4, b4,
      xcat, 256, nullptr);

  // ---- conv5 MFMA (tiled GEMM) + pool
  fc5_mfma<<<dim3(8,64),256,0,stream>>>(xcat, wb5, ws+o_st5, h5b);
  pool5_kernel<<<BB*32,256,0,stream>>>(x, h5b, ws+o_st5, g5, b5,
                                       (unsigned*)(ws+o_pmax), ws+o_psum);

  // ---- FC head
  fc6_kernel<<<512,256,0,stream>>>(x, (unsigned*)(ws+o_pmax), ws+o_psum, w6, g6, b6, ws+o_y6);
  fc7_kernel<<<256,256,0,stream>>>(x, ws+o_y6, w7, bias7, g7, b7, ws+o_y7);
  fc8_kernel<<<40,256,0,stream>>>(x, ws+o_y7, w8, bias8, d_out);
}